// Round 7
// baseline (766.878 us; speedup 1.0000x reference)
//
#include <hip/hip_runtime.h>
#include <hip/hip_cooperative_groups.h>
#include <stdint.h>

namespace cg = cooperative_groups;

// D = 128 fixed by the problem.
#define FD 128

typedef __bf16 bf16x8 __attribute__((ext_vector_type(8)));
typedef unsigned short u16x8 __attribute__((ext_vector_type(8)));
typedef float  f32x16 __attribute__((ext_vector_type(16)));

__device__ __forceinline__ unsigned short f2bf(float f) {
    unsigned u = __float_as_uint(f);
    unsigned r = u + 0x7fffu + ((u >> 16) & 1u);   // RNE
    return (unsigned short)(r >> 16);
}
__device__ __forceinline__ float bflo(unsigned u) { return __uint_as_float(u << 16); }
__device__ __forceinline__ float bfhi(unsigned u) { return __uint_as_float(u & 0xffff0000u); }

// ---------------------------------------------------------------------------
// Layouts (R6, kept):
//   A  [N][128] bf16 canonical (gate-rec term + bg).
//   BS [N][256] bf16: B row (gate-send) then S row (message + bs) per node.
// ---------------------------------------------------------------------------

// ---------------------------------------------------------------------------
// prep: weights -> Wf, bf16 in MFMA B-fragment order (unchanged).
// ---------------------------------------------------------------------------
__global__ __launch_bounds__(256) void prep_kernel(
    const float* __restrict__ Wg,
    const float* __restrict__ Ws,
    const float* __restrict__ Wr,
    unsigned short* __restrict__ Wf)
{
    int wid = blockIdx.x * 256 + threadIdx.x;      // 0 .. 65535
    if (wid >= 512 * 128) return;
    int j  = wid & 7;
    int l  = (wid >> 3) & 63;
    int kt = (wid >> 9) & 7;
    int ct = wid >> 12;                        // 0..15
    int k  = kt * 16 + (l >> 5) * 8 + j;       // 0..127
    int c  = ct * 32 + (l & 31);               // 0..511
    float v;
    if (c < 128)      v = Wg[k * FD + c];                    // Wg1
    else if (c < 256) v = Wg[(128 + k) * FD + (c - 128)];    // Wg2
    else if (c < 384) v = Ws[k * FD + (c - 256)];            // Ws
    else              v = Wr[k * FD + (c - 384)];            // Wr
    Wf[wid] = f2bf(v);
}

// ---------------------------------------------------------------------------
// gemm: [A|B|S|R] = h @ [Wg1|Wg2|Ws|Wr]  (N x 512 output, K = 128)
// R6 form verbatim (proven 66 us): LDS-stationary weights, grid (256,4),
// no hot-loop barriers, canonical 2-B epilogue stores into A / BS / out.
// ---------------------------------------------------------------------------
__global__ __launch_bounds__(256, 4) void gemm_kernel(
    const float* __restrict__ h,
    const unsigned short* __restrict__ Wf,
    const float* __restrict__ bg,
    const float* __restrict__ bs,
    const float* __restrict__ br,
    unsigned short* __restrict__ A,
    unsigned short* __restrict__ BS,
    float* __restrict__ out,
    int N)
{
    __shared__ unsigned short Bsh[16384];       // 32 KB: one weight quarter

    const int w    = blockIdx.y;                // 0..3: which weight matrix
    const int lane = threadIdx.x & 63;
    const int wid  = threadIdx.x >> 6;          // wave 0..3

    // ---- stage quarter w into LDS once: 8 passes x (256 threads x 16 B) ----
    {
        const unsigned short* src = Wf + (size_t)w * 16384 + (size_t)threadIdx.x * 8;
        unsigned short* dst = Bsh + (size_t)threadIdx.x * 8;
        #pragma unroll
        for (int p = 0; p < 8; ++p) {
            __builtin_amdgcn_global_load_lds(
                (const __attribute__((address_space(1))) void*)(src + p * 2048),
                (__attribute__((address_space(3))) void*)(dst + p * 2048),
                16, 0, 0);
        }
    }

    // per-wave constants
    const int col_l  = lane & 31;
    const int rhalf  = (lane >> 5) * 4;
    float bias[4];
    #pragma unroll
    for (int i = 0; i < 4; ++i) {
        int col = i * 32 + col_l;
        bias[i] = (w == 0) ? bg[col] : (w == 2) ? bs[col] : (w == 3) ? br[col] : 0.0f;
    }
    // bf16 destination (w = 0,1,2): base + row*rstride + col
    unsigned short* dst0 = (w == 0) ? A : (w == 2) ? (BS + 128) : BS;
    const size_t rstride = (w == 0) ? 128 : 256;

    __syncthreads();   // stage complete; no further barriers

    const int stride = gridDim.x * 128;         // rows per grid sweep (256*128)
    for (int rb0 = blockIdx.x * 128; rb0 < N; rb0 += stride) {
        const int rb = rb0 + wid * 32;
        int arow = rb + (lane & 31);
        if (arow >= N) arow = N - 1;      // clamp tail loads (dup work, guarded store)
        const float* aptr = h + (size_t)arow * FD + (lane >> 5) * 8;

        // A strip: 16 dwordx4, convert to 8 bf16x8 fragments
        bf16x8 afrag[8];
        #pragma unroll
        for (int kt = 0; kt < 8; ++kt) {
            float4 f0 = *(const float4*)(aptr + kt * 16);
            float4 f1 = *(const float4*)(aptr + kt * 16 + 4);
            union { u16x8 u; bf16x8 b; } cv;
            cv.u[0] = f2bf(f0.x); cv.u[1] = f2bf(f0.y);
            cv.u[2] = f2bf(f0.z); cv.u[3] = f2bf(f0.w);
            cv.u[4] = f2bf(f1.x); cv.u[5] = f2bf(f1.y);
            cv.u[6] = f2bf(f1.z); cv.u[7] = f2bf(f1.w);
            afrag[kt] = cv.b;
        }

        f32x16 acc[4];
        #pragma unroll
        for (int i = 0; i < 4; ++i)
            #pragma unroll
            for (int r = 0; r < 16; ++r) acc[i][r] = 0.0f;

        #pragma unroll
        for (int kt = 0; kt < 8; ++kt) {
            #pragma unroll
            for (int i = 0; i < 4; ++i) {
                bf16x8 bfr = *(const bf16x8*)(Bsh + (size_t)((i * 8 + kt) * 64 + lane) * 8);
                acc[i] = __builtin_amdgcn_mfma_f32_32x32x16_bf16(
                             afrag[kt], bfr, acc[i], 0, 0, 0);
            }
        }

        // C/D layout: col = lane&31, row = (reg&3) + 8*(reg>>2) + 4*(lane>>5)
        const bool interior = (rb + 32 <= N);
        if (w == 3) {
            #pragma unroll
            for (int i = 0; i < 4; ++i) {
                int col = i * 32 + col_l;
                #pragma unroll
                for (int r = 0; r < 16; ++r) {
                    int row = rb + (r & 3) + 8 * (r >> 2) + rhalf;
                    if (interior || row < N)
                        out[(size_t)row * FD + col] = acc[i][r] + bias[i];
                }
            }
        } else {
            #pragma unroll
            for (int i = 0; i < 4; ++i) {
                int col = i * 32 + col_l;
                #pragma unroll
                for (int r = 0; r < 16; ++r) {
                    int row = rb + (r & 3) + 8 * (r >> 2) + rhalf;
                    if (interior || row < N)
                        dst0[(size_t)row * rstride + col] = f2bf(acc[i][r] + bias[i]);
                }
            }
        }
    }
}

// ---------------------------------------------------------------------------
// csr_kernel (R7): the ENTIRE CSR build in one cooperative dispatch.
// Phases (grid.sync between): zero deg | hist | scan1 | scan2 | scan3 |
// scatter. Replaces 6 dispatches (memset,hist,scan1,scan2,scan3,scatter);
// the phase boundaries need device-wide ordering, which grid.sync provides
// without round-tripping the command processor. idx stays L2-resident
// across hist->scatter. Grid 1024 x 256 (4 blocks/CU, trivially resident).
// ---------------------------------------------------------------------------
__global__ __launch_bounds__(256) void csr_kernel(
    const int* __restrict__ idx,        // [2][E]
    int* __restrict__ deg,              // becomes off (segment ends) at exit
    int* __restrict__ partial,          // >= 256 ints
    int* __restrict__ csr,              // [E]
    int N, int E)
{
    cg::grid_group grid = cg::this_grid();
    __shared__ int sh[256];

    const int tid  = blockIdx.x * 256 + threadIdx.x;
    const int nthr = gridDim.x * 256;
    const int nb   = (N + 1023) / 1024;          // 98 chunks (<= 256)

    // P0: zero deg
    for (int i = tid; i < N; i += nthr) deg[i] = 0;
    grid.sync();

    // P1: histogram of receivers
    for (int e = tid; e < E; e += nthr) atomicAdd(&deg[idx[E + e]], 1);
    grid.sync();

    // P2: per-chunk sums (blocks < nb; 1024 elems each)
    if (blockIdx.x < nb) {
        int base = blockIdx.x * 1024 + threadIdx.x * 4;
        int s = 0;
        #pragma unroll
        for (int j = 0; j < 4; ++j) s += (base + j < N) ? deg[base + j] : 0;
        sh[threadIdx.x] = s;
        __syncthreads();
        for (int ofs = 128; ofs > 0; ofs >>= 1) {
            if (threadIdx.x < ofs) sh[threadIdx.x] += sh[threadIdx.x + ofs];
            __syncthreads();
        }
        if (threadIdx.x == 0) partial[blockIdx.x] = sh[0];
    }
    grid.sync();

    // P3: block 0 exclusive-scans the <=256 partials in place
    if (blockIdx.x == 0) {
        int t = threadIdx.x;
        int p = (t < nb) ? partial[t] : 0;
        sh[t] = p;
        __syncthreads();
        for (int ofs = 1; ofs < 256; ofs <<= 1) {
            int x = (t >= ofs) ? sh[t - ofs] : 0;
            __syncthreads();
            sh[t] += x;
            __syncthreads();
        }
        if (t < nb) partial[t] = sh[t] - p;   // exclusive
    }
    grid.sync();

    // P4: local exclusive scan + chunk offset; IN-PLACE deg -> off(start)
    if (blockIdx.x < nb) {
        int base = blockIdx.x * 1024 + threadIdx.x * 4;
        int v[4];
        #pragma unroll
        for (int j = 0; j < 4; ++j) v[j] = (base + j < N) ? deg[base + j] : 0;
        int tsum = v[0] + v[1] + v[2] + v[3];
        sh[threadIdx.x] = tsum;
        __syncthreads();
        for (int ofs = 1; ofs < 256; ofs <<= 1) {
            int x = (threadIdx.x >= ofs) ? sh[threadIdx.x - ofs] : 0;
            __syncthreads();
            sh[threadIdx.x] += x;
            __syncthreads();
        }
        int run = partial[blockIdx.x] + sh[threadIdx.x] - tsum;  // exclusive at base
        #pragma unroll
        for (int j = 0; j < 4; ++j) {
            if (base + j < N) deg[base + j] = run;
            run += v[j];
        }
    }
    grid.sync();

    // P5: scatter; consumes off (after: deg[r] = end of segment r)
    for (int e = tid; e < E; e += nthr) {
        int s = idx[e];
        int r = idx[E + e];
        int pos = atomicAdd(&deg[r], 1);
        csr[pos] = s;
    }
}

// ---------------------------------------------------------------------------
// aggregate: R6 form verbatim (proven 64 us): one wave per node, BS
// interleaved gather, 4-edge unroll, rcp-sigmoid, canonical float2 RMW.
// ---------------------------------------------------------------------------
__global__ __launch_bounds__(256) void aggregate_kernel(
    const int* __restrict__ off,          // consumed: off[r] = segment end
    const int* __restrict__ csr,
    const unsigned* __restrict__ A,       // bf16x2 per uint, [N][64]
    const unsigned* __restrict__ BS,      // bf16x2 per uint, [N][128] (B|S)
    float* __restrict__ out,
    int N)
{
    int r = blockIdx.x * 4 + (threadIdx.x >> 6);
    if (r >= N) return;
    int lane = threadIdx.x & 63;

    int start = (r == 0) ? 0 : off[r - 1];
    int end   = off[r];
    if (start >= end) return;             // deg 0: out already holds R

    unsigned ua = A[(size_t)r * 64 + lane];
    float a0 = bflo(ua), a1 = bfhi(ua);
    float acc0 = 0.0f, acc1 = 0.0f;

    int i = start;
    for (; i + 3 < end; i += 4) {
        int s0 = csr[i], s1 = csr[i + 1], s2 = csr[i + 2], s3 = csr[i + 3];
        unsigned ub0 = BS[(size_t)s0 * 128 + lane];
        unsigned us0 = BS[(size_t)s0 * 128 + 64 + lane];
        unsigned ub1 = BS[(size_t)s1 * 128 + lane];
        unsigned us1 = BS[(size_t)s1 * 128 + 64 + lane];
        unsigned ub2 = BS[(size_t)s2 * 128 + lane];
        unsigned us2 = BS[(size_t)s2 * 128 + 64 + lane];
        unsigned ub3 = BS[(size_t)s3 * 128 + lane];
        unsigned us3 = BS[(size_t)s3 * 128 + 64 + lane];
        acc0 += bflo(us0) * __builtin_amdgcn_rcpf(1.0f + __expf(-(a0 + bflo(ub0))));
        acc1 += bfhi(us0) * __builtin_amdgcn_rcpf(1.0f + __expf(-(a1 + bfhi(ub0))));
        acc0 += bflo(us1) * __builtin_amdgcn_rcpf(1.0f + __expf(-(a0 + bflo(ub1))));
        acc1 += bfhi(us1) * __builtin_amdgcn_rcpf(1.0f + __expf(-(a1 + bfhi(ub1))));
        acc0 += bflo(us2) * __builtin_amdgcn_rcpf(1.0f + __expf(-(a0 + bflo(ub2))));
        acc1 += bfhi(us2) * __builtin_amdgcn_rcpf(1.0f + __expf(-(a1 + bfhi(ub2))));
        acc0 += bflo(us3) * __builtin_amdgcn_rcpf(1.0f + __expf(-(a0 + bflo(ub3))));
        acc1 += bfhi(us3) * __builtin_amdgcn_rcpf(1.0f + __expf(-(a1 + bfhi(ub3))));
    }
    for (; i < end; ++i) {
        int s0 = csr[i];
        unsigned ub0 = BS[(size_t)s0 * 128 + lane];
        unsigned us0 = BS[(size_t)s0 * 128 + 64 + lane];
        acc0 += bflo(us0) * __builtin_amdgcn_rcpf(1.0f + __expf(-(a0 + bflo(ub0))));
        acc1 += bfhi(us0) * __builtin_amdgcn_rcpf(1.0f + __expf(-(a1 + bfhi(ub0))));
    }

    float2* o = (float2*)(out + (size_t)r * FD + 2 * lane);
    float2 cur = *o;
    cur.x += acc0;
    cur.y += acc1;
    *o = cur;
}

// ---------------------------------------------------------------------------
extern "C" void kernel_launch(void* const* d_in, const int* in_sizes, int n_in,
                              void* d_out, int out_size, void* d_ws, size_t ws_size,
                              hipStream_t stream)
{
    const float* h  = (const float*)d_in[0];
    const int*   ei = (const int*)d_in[1];      // int32 per harness contract
    const float* Wg = (const float*)d_in[2];
    const float* bg = (const float*)d_in[3];
    const float* Ws = (const float*)d_in[4];
    const float* bs = (const float*)d_in[5];
    const float* Wr = (const float*)d_in[6];
    const float* br = (const float*)d_in[7];
    float* out = (float*)d_out;

    const int N = in_sizes[0] / FD;       // 100000
    const int E = in_sizes[1] / 2;        // 600000

    // Workspace layout:
    //   Wf [512*128 bf16] | A [N*128 bf16] | BS [N*256 bf16] | deg/off [N int]
    //   | partial [256 int] | csr [E int]
    unsigned short* Wf  = (unsigned short*)d_ws;
    unsigned short* Abf = Wf + 512 * FD;
    unsigned short* BSb = Abf + (size_t)N * FD;
    int* deg     = (int*)(BSb + (size_t)N * 2 * FD);   // becomes off
    int* partial = deg + N;
    int* csr     = partial + 256;

    size_t need = (size_t)(512 * FD + 3ull * N * FD) * 2 + ((size_t)N + 256 + E) * 4;
    if (ws_size < need) return;   // diagnostic: absmax will equal memset-0 baseline

    const int nb = (N + 1023) / 1024;     // 98 scan chunks (<= 256 required)
    if (nb > 256) return;

    prep_kernel<<<(512 * FD + 255) / 256, 256, 0, stream>>>(Wg, Ws, Wr, Wf);
    dim3 ggrid(256, 4);                   // 1024 blocks = 4 blocks/CU
    gemm_kernel<<<ggrid, 256, 0, stream>>>(h, Wf, bg, bs, br,
                                           Abf, BSb, out, N);

    // CSR build: one cooperative dispatch (zero|hist|scan|scatter).
    {
        int n = N, e = E;
        void* args[] = { (void*)&ei, (void*)&deg, (void*)&partial,
                         (void*)&csr, (void*)&n, (void*)&e };
        hipLaunchCooperativeKernel((const void*)csr_kernel,
                                   dim3(1024), dim3(256), args, 0, stream);
    }

    aggregate_kernel<<<(N + 3) / 4, 256, 0, stream>>>(deg, csr,
                                                      (const unsigned*)Abf,
                                                      (const unsigned*)BSb,
                                                      out, N);
}

// Round 8
// 653.242 us; speedup vs baseline: 1.1740x; 1.1740x over previous
//
#include <hip/hip_runtime.h>
#include <stdint.h>

// D = 128 fixed by the problem.
#define FD 128

typedef __bf16 bf16x8 __attribute__((ext_vector_type(8)));
typedef unsigned short u16x8 __attribute__((ext_vector_type(8)));
typedef float  f32x16 __attribute__((ext_vector_type(16)));

__device__ __forceinline__ unsigned short f2bf(float f) {
    unsigned u = __float_as_uint(f);
    unsigned r = u + 0x7fffu + ((u >> 16) & 1u);   // RNE
    return (unsigned short)(r >> 16);
}
__device__ __forceinline__ float bflo(unsigned u) { return __uint_as_float(u << 16); }
__device__ __forceinline__ float bfhi(unsigned u) { return __uint_as_float(u & 0xffff0000u); }

// ---------------------------------------------------------------------------
// Layouts (R6, kept):
//   A  [N][128] bf16 canonical (gate-rec term + bg folded).
//   BS [N][256] bf16: B row (gate-send) then S row (message + bs) per node.
//
// R8: the CSR build (memset, hist, scan1, scan2, scan3, scatter -- 6
// dispatches) is DELETED. R7 measured grid.sync at ~100 us/sync (dead end)
// but also showed the CSR work itself is tiny (62 MB); the ~150 us residual
// was dispatch boundaries. Aggregate is now EDGE-PARALLEL with device-scope
// fp32 atomicAdd into out (random receivers -> low contention; additive
// reorder is within the 0.0625 tolerance). Pipeline: prep -> gemm -> edge_agg.
// ---------------------------------------------------------------------------

// ---------------------------------------------------------------------------
// prep: weights -> Wf, bf16 in MFMA B-fragment order (unchanged).
// ---------------------------------------------------------------------------
__global__ __launch_bounds__(256) void prep_kernel(
    const float* __restrict__ Wg,
    const float* __restrict__ Ws,
    const float* __restrict__ Wr,
    unsigned short* __restrict__ Wf)
{
    int wid = blockIdx.x * 256 + threadIdx.x;      // 0 .. 65535
    if (wid >= 512 * 128) return;
    int j  = wid & 7;
    int l  = (wid >> 3) & 63;
    int kt = (wid >> 9) & 7;
    int ct = wid >> 12;                        // 0..15
    int k  = kt * 16 + (l >> 5) * 8 + j;       // 0..127
    int c  = ct * 32 + (l & 31);               // 0..511
    float v;
    if (c < 128)      v = Wg[k * FD + c];                    // Wg1
    else if (c < 256) v = Wg[(128 + k) * FD + (c - 128)];    // Wg2
    else if (c < 384) v = Ws[k * FD + (c - 256)];            // Ws
    else              v = Wr[k * FD + (c - 384)];            // Wr
    Wf[wid] = f2bf(v);
}

// ---------------------------------------------------------------------------
// gemm: [A|B|S|R] = h @ [Wg1|Wg2|Ws|Wr]  (N x 512 output, K = 128)
// R6 form verbatim (proven 66 us): LDS-stationary weights, grid (256,4),
// no hot-loop barriers, canonical 2-B epilogue stores into A / BS / out.
// ---------------------------------------------------------------------------
__global__ __launch_bounds__(256, 4) void gemm_kernel(
    const float* __restrict__ h,
    const unsigned short* __restrict__ Wf,
    const float* __restrict__ bg,
    const float* __restrict__ bs,
    const float* __restrict__ br,
    unsigned short* __restrict__ A,
    unsigned short* __restrict__ BS,
    float* __restrict__ out,
    int N)
{
    __shared__ unsigned short Bsh[16384];       // 32 KB: one weight quarter

    const int w    = blockIdx.y;                // 0..3: which weight matrix
    const int lane = threadIdx.x & 63;
    const int wid  = threadIdx.x >> 6;          // wave 0..3

    // ---- stage quarter w into LDS once: 8 passes x (256 threads x 16 B) ----
    {
        const unsigned short* src = Wf + (size_t)w * 16384 + (size_t)threadIdx.x * 8;
        unsigned short* dst = Bsh + (size_t)threadIdx.x * 8;
        #pragma unroll
        for (int p = 0; p < 8; ++p) {
            __builtin_amdgcn_global_load_lds(
                (const __attribute__((address_space(1))) void*)(src + p * 2048),
                (__attribute__((address_space(3))) void*)(dst + p * 2048),
                16, 0, 0);
        }
    }

    // per-wave constants
    const int col_l  = lane & 31;
    const int rhalf  = (lane >> 5) * 4;
    float bias[4];
    #pragma unroll
    for (int i = 0; i < 4; ++i) {
        int col = i * 32 + col_l;
        bias[i] = (w == 0) ? bg[col] : (w == 2) ? bs[col] : (w == 3) ? br[col] : 0.0f;
    }
    // bf16 destination (w = 0,1,2): base + row*rstride + col
    unsigned short* dst0 = (w == 0) ? A : (w == 2) ? (BS + 128) : BS;
    const size_t rstride = (w == 0) ? 128 : 256;

    __syncthreads();   // stage complete; no further barriers

    const int stride = gridDim.x * 128;         // rows per grid sweep (256*128)
    for (int rb0 = blockIdx.x * 128; rb0 < N; rb0 += stride) {
        const int rb = rb0 + wid * 32;
        int arow = rb + (lane & 31);
        if (arow >= N) arow = N - 1;      // clamp tail loads (dup work, guarded store)
        const float* aptr = h + (size_t)arow * FD + (lane >> 5) * 8;

        // A strip: 16 dwordx4, convert to 8 bf16x8 fragments
        bf16x8 afrag[8];
        #pragma unroll
        for (int kt = 0; kt < 8; ++kt) {
            float4 f0 = *(const float4*)(aptr + kt * 16);
            float4 f1 = *(const float4*)(aptr + kt * 16 + 4);
            union { u16x8 u; bf16x8 b; } cv;
            cv.u[0] = f2bf(f0.x); cv.u[1] = f2bf(f0.y);
            cv.u[2] = f2bf(f0.z); cv.u[3] = f2bf(f0.w);
            cv.u[4] = f2bf(f1.x); cv.u[5] = f2bf(f1.y);
            cv.u[6] = f2bf(f1.z); cv.u[7] = f2bf(f1.w);
            afrag[kt] = cv.b;
        }

        f32x16 acc[4];
        #pragma unroll
        for (int i = 0; i < 4; ++i)
            #pragma unroll
            for (int r = 0; r < 16; ++r) acc[i][r] = 0.0f;

        #pragma unroll
        for (int kt = 0; kt < 8; ++kt) {
            #pragma unroll
            for (int i = 0; i < 4; ++i) {
                bf16x8 bfr = *(const bf16x8*)(Bsh + (size_t)((i * 8 + kt) * 64 + lane) * 8);
                acc[i] = __builtin_amdgcn_mfma_f32_32x32x16_bf16(
                             afrag[kt], bfr, acc[i], 0, 0, 0);
            }
        }

        // C/D layout: col = lane&31, row = (reg&3) + 8*(reg>>2) + 4*(lane>>5)
        const bool interior = (rb + 32 <= N);
        if (w == 3) {
            #pragma unroll
            for (int i = 0; i < 4; ++i) {
                int col = i * 32 + col_l;
                #pragma unroll
                for (int r = 0; r < 16; ++r) {
                    int row = rb + (r & 3) + 8 * (r >> 2) + rhalf;
                    if (interior || row < N)
                        out[(size_t)row * FD + col] = acc[i][r] + bias[i];
                }
            }
        } else {
            #pragma unroll
            for (int i = 0; i < 4; ++i) {
                int col = i * 32 + col_l;
                #pragma unroll
                for (int r = 0; r < 16; ++r) {
                    int row = rb + (r & 3) + 8 * (r >> 2) + rhalf;
                    if (interior || row < N)
                        dst0[(size_t)row * rstride + col] = f2bf(acc[i][r] + bias[i]);
                }
            }
        }
    }
}

// ---------------------------------------------------------------------------
// edge_agg (R8): one wave per edge, grid-stride. Lane covers feature pair
// (2l, 2l+1). Per edge: gather A[r] (256 B) + BS[s] (512 B), gate, then
// 2 fp32 atomicAdds per lane into out[r] (device-scope, random receivers).
// Replaces memset+hist+scan1+scan2+scan3+scatter+aggregate (6 dispatches
// + CSR traffic) with one dispatch.
// ---------------------------------------------------------------------------
__global__ __launch_bounds__(256) void edge_agg_kernel(
    const int* __restrict__ idx,          // [2][E]
    const unsigned* __restrict__ A,       // bf16x2 per uint, [N][64]
    const unsigned* __restrict__ BS,      // bf16x2 per uint, [N][128] (B|S)
    float* __restrict__ out,
    int E)
{
    const int lane = threadIdx.x & 63;
    const int wv   = (blockIdx.x * 256 + threadIdx.x) >> 6;   // global wave id
    const int nwv  = (gridDim.x * 256) >> 6;

    for (int e = wv; e < E; e += nwv) {
        int s = idx[e];
        int r = idx[E + e];
        unsigned ua = A[(size_t)r * 64 + lane];
        unsigned ub = BS[(size_t)s * 128 + lane];
        unsigned us = BS[(size_t)s * 128 + 64 + lane];
        float g0 = bflo(ua) + bflo(ub);
        float g1 = bfhi(ua) + bfhi(ub);
        float m0 = bflo(us) * __builtin_amdgcn_rcpf(1.0f + __expf(-g0));
        float m1 = bfhi(us) * __builtin_amdgcn_rcpf(1.0f + __expf(-g1));
        float* o = out + (size_t)r * FD + 2 * lane;
        atomicAdd(o,     m0);
        atomicAdd(o + 1, m1);
    }
}

// ---------------------------------------------------------------------------
extern "C" void kernel_launch(void* const* d_in, const int* in_sizes, int n_in,
                              void* d_out, int out_size, void* d_ws, size_t ws_size,
                              hipStream_t stream)
{
    const float* h  = (const float*)d_in[0];
    const int*   ei = (const int*)d_in[1];      // int32 per harness contract
    const float* Wg = (const float*)d_in[2];
    const float* bg = (const float*)d_in[3];
    const float* Ws = (const float*)d_in[4];
    const float* bs = (const float*)d_in[5];
    const float* Wr = (const float*)d_in[6];
    const float* br = (const float*)d_in[7];
    float* out = (float*)d_out;

    const int N = in_sizes[0] / FD;       // 100000
    const int E = in_sizes[1] / 2;        // 600000

    // Workspace layout: Wf [512*128 bf16] | A [N*128 bf16] | BS [N*256 bf16]
    unsigned short* Wf  = (unsigned short*)d_ws;
    unsigned short* Abf = Wf + 512 * FD;
    unsigned short* BSb = Abf + (size_t)N * FD;

    size_t need = (size_t)(512 * FD + 3ull * N * FD) * 2;
    if (ws_size < need) return;   // diagnostic: absmax will equal memset-0 baseline

    prep_kernel<<<(512 * FD + 255) / 256, 256, 0, stream>>>(Wg, Ws, Wr, Wf);
    dim3 ggrid(256, 4);                   // 1024 blocks = 4 blocks/CU
    gemm_kernel<<<ggrid, 256, 0, stream>>>(h, Wf, bg, bs, br,
                                           Abf, BSb, out, N);
    edge_agg_kernel<<<2048, 256, 0, stream>>>(ei,
                                              (const unsigned*)Abf,
                                              (const unsigned*)BSb,
                                              out, E);
}

// Round 9
// 270.695 us; speedup vs baseline: 2.8330x; 2.4132x over previous
//
#include <hip/hip_runtime.h>
#include <stdint.h>

// D = 128 fixed by the problem.
#define FD 128

typedef __bf16 bf16x8 __attribute__((ext_vector_type(8)));
typedef unsigned short u16x8 __attribute__((ext_vector_type(8)));
typedef float  f32x16 __attribute__((ext_vector_type(16)));

__device__ __forceinline__ unsigned short f2bf(float f) {
    unsigned u = __float_as_uint(f);
    unsigned r = u + 0x7fffu + ((u >> 16) & 1u);   // RNE
    return (unsigned short)(r >> 16);
}
__device__ __forceinline__ float bflo(unsigned u) { return __uint_as_float(u << 16); }
__device__ __forceinline__ float bfhi(unsigned u) { return __uint_as_float(u & 0xffff0000u); }

// ---------------------------------------------------------------------------
// Layouts (R6, kept):
//   A  [N][128] bf16 canonical (gate-rec term + bg folded).
//   BS [N][256] bf16: B row (gate-send) then S row (message + bs) per node.
//
// R9: same work as R6 (best: 283 us), dispatch count 9 -> 5.
//  - memset folded into prep (prep threads also zero deg/partial).
//  - hist folded into the gemm dispatch as blockIdx.y == 4 (independent
//    work; needs only zeroed deg, guaranteed by the dispatch boundary).
//  - scan1/2/3 fused into ONE single-pass kernel via decoupled lookback:
//    device-scope atomics are memory-side on gfx950 (R8 measurement), hence
//    coherent across XCDs; 98 blocks are trivially co-resident, no deadlock.
//  - scatter, aggregate unchanged (proven forms).
// R7 showed grid.sync costs ~100 us at this grid size (dead end); R8 showed
// per-feature fp32 atomics go to HBM (496 us; dead end). This keeps the
// atomic-free feature path and attacks only the dispatch-boundary overhead.
// ---------------------------------------------------------------------------

// ---------------------------------------------------------------------------
// prep: weights -> Wf (bf16, MFMA B-fragment order) + zero deg/partial.
//   Wf[((ct*8 + kt)*64 + lane)*8 + j] = W'[k = kt*16 + (lane>>5)*8 + j]
//                                         [c = ct*32 + (lane&31)]
// W' = [Wg1 | Wg2 | Ws | Wr] (128 x 512); quarter w contiguous at w*16384.
// ---------------------------------------------------------------------------
__global__ __launch_bounds__(256) void prep_kernel(
    const float* __restrict__ Wg,
    const float* __restrict__ Ws,
    const float* __restrict__ Wr,
    unsigned short* __restrict__ Wf,
    int* __restrict__ deg,
    int* __restrict__ partial,
    int N)
{
    int wid = blockIdx.x * 256 + threadIdx.x;      // 0 .. 65535
    // zero deg (N ints) and partial (256 ints) for the CSR build
    for (int i = wid; i < N; i += 65536) deg[i] = 0;
    if (wid < 256) partial[wid] = 0;
    if (wid >= 512 * 128) return;
    int j  = wid & 7;
    int l  = (wid >> 3) & 63;
    int kt = (wid >> 9) & 7;
    int ct = wid >> 12;                        // 0..15
    int k  = kt * 16 + (l >> 5) * 8 + j;       // 0..127
    int c  = ct * 32 + (l & 31);               // 0..511
    float v;
    if (c < 128)      v = Wg[k * FD + c];                    // Wg1
    else if (c < 256) v = Wg[(128 + k) * FD + (c - 128)];    // Wg2
    else if (c < 384) v = Ws[k * FD + (c - 256)];            // Ws
    else              v = Wr[k * FD + (c - 384)];            // Wr
    Wf[wid] = f2bf(v);
}

// ---------------------------------------------------------------------------
// gemm (+hist slice): [A|B|S|R] = h @ [Wg1|Wg2|Ws|Wr]  (N x 512, K = 128)
// blockIdx.y == 0..3: R6 gemm verbatim (LDS-stationary weights, grid-stride,
// no hot-loop barriers). blockIdx.y == 4: receiver histogram (256 blocks,
// grid-stride over E, device-scope int atomics -- independent of gemm).
// ---------------------------------------------------------------------------
__global__ __launch_bounds__(256, 4) void gemm_kernel(
    const float* __restrict__ h,
    const unsigned short* __restrict__ Wf,
    const float* __restrict__ bg,
    const float* __restrict__ bs,
    const float* __restrict__ br,
    unsigned short* __restrict__ A,
    unsigned short* __restrict__ BS,
    float* __restrict__ out,
    const int* __restrict__ idx,
    int* __restrict__ deg,
    int N, int E)
{
    __shared__ unsigned short Bsh[16384];       // 32 KB: one weight quarter

    if (blockIdx.y == 4) {
        // hist slice: 256 blocks x 256 threads
        int t = blockIdx.x * 256 + threadIdx.x;
        for (int e = t; e < E; e += 65536) atomicAdd(&deg[idx[E + e]], 1);
        return;
    }

    const int w    = blockIdx.y;                // 0..3: which weight matrix
    const int lane = threadIdx.x & 63;
    const int wid  = threadIdx.x >> 6;          // wave 0..3

    // ---- stage quarter w into LDS once: 8 passes x (256 threads x 16 B) ----
    {
        const unsigned short* src = Wf + (size_t)w * 16384 + (size_t)threadIdx.x * 8;
        unsigned short* dst = Bsh + (size_t)threadIdx.x * 8;
        #pragma unroll
        for (int p = 0; p < 8; ++p) {
            __builtin_amdgcn_global_load_lds(
                (const __attribute__((address_space(1))) void*)(src + p * 2048),
                (__attribute__((address_space(3))) void*)(dst + p * 2048),
                16, 0, 0);
        }
    }

    // per-wave constants
    const int col_l  = lane & 31;
    const int rhalf  = (lane >> 5) * 4;
    float bias[4];
    #pragma unroll
    for (int i = 0; i < 4; ++i) {
        int col = i * 32 + col_l;
        bias[i] = (w == 0) ? bg[col] : (w == 2) ? bs[col] : (w == 3) ? br[col] : 0.0f;
    }
    // bf16 destination (w = 0,1,2): base + row*rstride + col
    unsigned short* dst0 = (w == 0) ? A : (w == 2) ? (BS + 128) : BS;
    const size_t rstride = (w == 0) ? 128 : 256;

    __syncthreads();   // stage complete; no further barriers

    const int stride = gridDim.x * 128;         // rows per grid sweep (256*128)
    for (int rb0 = blockIdx.x * 128; rb0 < N; rb0 += stride) {
        const int rb = rb0 + wid * 32;
        int arow = rb + (lane & 31);
        if (arow >= N) arow = N - 1;      // clamp tail loads (dup work, guarded store)
        const float* aptr = h + (size_t)arow * FD + (lane >> 5) * 8;

        // A strip: 16 dwordx4, convert to 8 bf16x8 fragments
        bf16x8 afrag[8];
        #pragma unroll
        for (int kt = 0; kt < 8; ++kt) {
            float4 f0 = *(const float4*)(aptr + kt * 16);
            float4 f1 = *(const float4*)(aptr + kt * 16 + 4);
            union { u16x8 u; bf16x8 b; } cv;
            cv.u[0] = f2bf(f0.x); cv.u[1] = f2bf(f0.y);
            cv.u[2] = f2bf(f0.z); cv.u[3] = f2bf(f0.w);
            cv.u[4] = f2bf(f1.x); cv.u[5] = f2bf(f1.y);
            cv.u[6] = f2bf(f1.z); cv.u[7] = f2bf(f1.w);
            afrag[kt] = cv.b;
        }

        f32x16 acc[4];
        #pragma unroll
        for (int i = 0; i < 4; ++i)
            #pragma unroll
            for (int r = 0; r < 16; ++r) acc[i][r] = 0.0f;

        #pragma unroll
        for (int kt = 0; kt < 8; ++kt) {
            #pragma unroll
            for (int i = 0; i < 4; ++i) {
                bf16x8 bfr = *(const bf16x8*)(Bsh + (size_t)((i * 8 + kt) * 64 + lane) * 8);
                acc[i] = __builtin_amdgcn_mfma_f32_32x32x16_bf16(
                             afrag[kt], bfr, acc[i], 0, 0, 0);
            }
        }

        // C/D layout: col = lane&31, row = (reg&3) + 8*(reg>>2) + 4*(lane>>5)
        const bool interior = (rb + 32 <= N);
        if (w == 3) {
            #pragma unroll
            for (int i = 0; i < 4; ++i) {
                int col = i * 32 + col_l;
                #pragma unroll
                for (int r = 0; r < 16; ++r) {
                    int row = rb + (r & 3) + 8 * (r >> 2) + rhalf;
                    if (interior || row < N)
                        out[(size_t)row * FD + col] = acc[i][r] + bias[i];
                }
            }
        } else {
            #pragma unroll
            for (int i = 0; i < 4; ++i) {
                int col = i * 32 + col_l;
                #pragma unroll
                for (int r = 0; r < 16; ++r) {
                    int row = rb + (r & 3) + 8 * (r >> 2) + rhalf;
                    if (interior || row < N)
                        dst0[(size_t)row * rstride + col] = f2bf(acc[i][r] + bias[i]);
                }
            }
        }
    }
}

// ---------------------------------------------------------------------------
// scan_kernel (R9): single-pass exclusive scan of deg[N] via decoupled
// lookback. Block b scans its 1024-chunk locally, publishes flag|aggregate
// to partial[b] (device-scope atomicExch -> memory-side, coherent), then
// thread t<b spin-reads partial[t]; LDS-reduce of predecessor aggregates
// gives the chunk prefix. All 98 blocks co-resident -> no deadlock.
// Replaces scan1+scan2+scan3. deg becomes segment-START offsets in place.
// ---------------------------------------------------------------------------
__global__ __launch_bounds__(256) void scan_kernel(
    int* __restrict__ deg, unsigned* __restrict__ partial, int N)
{
    __shared__ int sh[256];
    __shared__ int sh2[256];
    const int bid = blockIdx.x;
    const int tid = threadIdx.x;
    int base = bid * 1024 + tid * 4;
    int v[4];
    #pragma unroll
    for (int j = 0; j < 4; ++j) v[j] = (base + j < N) ? deg[base + j] : 0;
    int tsum = v[0] + v[1] + v[2] + v[3];
    sh[tid] = tsum;
    __syncthreads();
    for (int ofs = 1; ofs < 256; ofs <<= 1) {
        int x = (tid >= ofs) ? sh[tid - ofs] : 0;
        __syncthreads();
        sh[tid] += x;
        __syncthreads();
    }
    // publish this chunk's aggregate (flag bit 31; aggregate <= E < 2^31)
    if (tid == 0) atomicExch(&partial[bid], 0x80000000u | (unsigned)sh[255]);
    // lookback: predecessor t's aggregate
    int myagg = 0;
    if (tid < bid) {
        unsigned p;
        do { p = atomicAdd(&partial[tid], 0u); } while (!(p & 0x80000000u));
        myagg = (int)(p & 0x7fffffffu);
    }
    sh2[tid] = myagg;
    __syncthreads();
    for (int ofs = 128; ofs > 0; ofs >>= 1) {
        if (tid < ofs) sh2[tid] += sh2[tid + ofs];
        __syncthreads();
    }
    int run = sh2[0] + sh[tid] - tsum;     // global exclusive prefix at base
    #pragma unroll
    for (int j = 0; j < 4; ++j) {
        if (base + j < N) deg[base + j] = run;
        run += v[j];
    }
}

// scatter: csr[pos] = send, consuming off (after: off[r] = end of segment r;
// start of segment r = (r==0) ? 0 : off[r-1])
__global__ __launch_bounds__(256) void scatter_kernel(
    const int* __restrict__ idx, int* __restrict__ off,
    int* __restrict__ csr, int E)
{
    int e = blockIdx.x * 256 + threadIdx.x;
    if (e >= E) return;
    int s = idx[e];
    int r = idx[E + e];
    int pos = atomicAdd(&off[r], 1);
    csr[pos] = s;
}

// ---------------------------------------------------------------------------
// aggregate: R6 form verbatim (proven 64 us): one wave per node, BS
// interleaved gather, 4-edge unroll, rcp-sigmoid, canonical float2 RMW.
// ---------------------------------------------------------------------------
__global__ __launch_bounds__(256) void aggregate_kernel(
    const int* __restrict__ off,          // consumed: off[r] = segment end
    const int* __restrict__ csr,
    const unsigned* __restrict__ A,       // bf16x2 per uint, [N][64]
    const unsigned* __restrict__ BS,      // bf16x2 per uint, [N][128] (B|S)
    float* __restrict__ out,
    int N)
{
    int r = blockIdx.x * 4 + (threadIdx.x >> 6);
    if (r >= N) return;
    int lane = threadIdx.x & 63;

    int start = (r == 0) ? 0 : off[r - 1];
    int end   = off[r];
    if (start >= end) return;             // deg 0: out already holds R

    unsigned ua = A[(size_t)r * 64 + lane];
    float a0 = bflo(ua), a1 = bfhi(ua);
    float acc0 = 0.0f, acc1 = 0.0f;

    int i = start;
    for (; i + 3 < end; i += 4) {
        int s0 = csr[i], s1 = csr[i + 1], s2 = csr[i + 2], s3 = csr[i + 3];
        unsigned ub0 = BS[(size_t)s0 * 128 + lane];
        unsigned us0 = BS[(size_t)s0 * 128 + 64 + lane];
        unsigned ub1 = BS[(size_t)s1 * 128 + lane];
        unsigned us1 = BS[(size_t)s1 * 128 + 64 + lane];
        unsigned ub2 = BS[(size_t)s2 * 128 + lane];
        unsigned us2 = BS[(size_t)s2 * 128 + 64 + lane];
        unsigned ub3 = BS[(size_t)s3 * 128 + lane];
        unsigned us3 = BS[(size_t)s3 * 128 + 64 + lane];
        acc0 += bflo(us0) * __builtin_amdgcn_rcpf(1.0f + __expf(-(a0 + bflo(ub0))));
        acc1 += bfhi(us0) * __builtin_amdgcn_rcpf(1.0f + __expf(-(a1 + bfhi(ub0))));
        acc0 += bflo(us1) * __builtin_amdgcn_rcpf(1.0f + __expf(-(a0 + bflo(ub1))));
        acc1 += bfhi(us1) * __builtin_amdgcn_rcpf(1.0f + __expf(-(a1 + bfhi(ub1))));
        acc0 += bflo(us2) * __builtin_amdgcn_rcpf(1.0f + __expf(-(a0 + bflo(ub2))));
        acc1 += bfhi(us2) * __builtin_amdgcn_rcpf(1.0f + __expf(-(a1 + bfhi(ub2))));
        acc0 += bflo(us3) * __builtin_amdgcn_rcpf(1.0f + __expf(-(a0 + bflo(ub3))));
        acc1 += bfhi(us3) * __builtin_amdgcn_rcpf(1.0f + __expf(-(a1 + bfhi(ub3))));
    }
    for (; i < end; ++i) {
        int s0 = csr[i];
        unsigned ub0 = BS[(size_t)s0 * 128 + lane];
        unsigned us0 = BS[(size_t)s0 * 128 + 64 + lane];
        acc0 += bflo(us0) * __builtin_amdgcn_rcpf(1.0f + __expf(-(a0 + bflo(ub0))));
        acc1 += bfhi(us0) * __builtin_amdgcn_rcpf(1.0f + __expf(-(a1 + bfhi(ub0))));
    }

    float2* o = (float2*)(out + (size_t)r * FD + 2 * lane);
    float2 cur = *o;
    cur.x += acc0;
    cur.y += acc1;
    *o = cur;
}

// ---------------------------------------------------------------------------
extern "C" void kernel_launch(void* const* d_in, const int* in_sizes, int n_in,
                              void* d_out, int out_size, void* d_ws, size_t ws_size,
                              hipStream_t stream)
{
    const float* h  = (const float*)d_in[0];
    const int*   ei = (const int*)d_in[1];      // int32 per harness contract
    const float* Wg = (const float*)d_in[2];
    const float* bg = (const float*)d_in[3];
    const float* Ws = (const float*)d_in[4];
    const float* bs = (const float*)d_in[5];
    const float* Wr = (const float*)d_in[6];
    const float* br = (const float*)d_in[7];
    float* out = (float*)d_out;

    const int N = in_sizes[0] / FD;       // 100000
    const int E = in_sizes[1] / 2;        // 600000

    // Workspace layout:
    //   Wf [512*128 bf16] | A [N*128 bf16] | BS [N*256 bf16] | deg/off [N int]
    //   | partial [256 int] | csr [E int]
    unsigned short* Wf  = (unsigned short*)d_ws;
    unsigned short* Abf = Wf + 512 * FD;
    unsigned short* BSb = Abf + (size_t)N * FD;
    int* deg     = (int*)(BSb + (size_t)N * 2 * FD);   // becomes off
    int* partial = deg + N;
    int* csr     = partial + 256;

    size_t need = (size_t)(512 * FD + 3ull * N * FD) * 2 + ((size_t)N + 256 + E) * 4;
    if (ws_size < need) return;   // diagnostic: absmax will equal memset-0 baseline

    const int nb = (N + 1023) / 1024;     // 98 scan chunks (<= 256 required)
    if (nb > 256) return;

    prep_kernel<<<256, 256, 0, stream>>>(Wg, Ws, Wr, Wf, deg, partial, N);
    dim3 ggrid(256, 5);                   // y=0..3 gemm (4 blocks/CU), y=4 hist
    gemm_kernel<<<ggrid, 256, 0, stream>>>(h, Wf, bg, bs, br,
                                           Abf, BSb, out, ei, deg, N, E);
    scan_kernel<<<nb, 256, 0, stream>>>(deg, (unsigned*)partial, N);
    scatter_kernel<<<(E + 255) / 256, 256, 0, stream>>>(ei, deg, csr, E);
    aggregate_kernel<<<(N + 3) / 4, 256, 0, stream>>>(deg, csr,
                                                      (const unsigned*)Abf,
                                                      (const unsigned*)BSb,
                                                      out, N);
}